// Round 6
// baseline (320.334 us; speedup 1.0000x reference)
//
#include <hip/hip_runtime.h>
#include <hip/hip_bf16.h>

#define NN 65536
#define EE 1048576
#define BG 64
#define NPGC 1024
#define KKEEP 820

typedef unsigned short u16;
typedef unsigned int u32;
typedef __attribute__((ext_vector_type(4))) float f32x4;
typedef __attribute__((ext_vector_type(8))) short bf16x8;

__device__ __forceinline__ float bfu_lo(u32 u) {  // low bf16 -> f32
    u32 x = u << 16;
    return __builtin_bit_cast(float, x);
}
__device__ __forceinline__ float bfu_hi(u32 u) {  // high bf16 -> f32
    u32 x = u & 0xffff0000u;
    return __builtin_bit_cast(float, x);
}
__device__ __forceinline__ u16 fbf(float f) {
    __hip_bfloat16 h = __float2bfloat16(f);
    return __builtin_bit_cast(u16, h);
}

// ---------------- CSR build ----------------
__global__ void deg_count_kernel(const int* __restrict__ dst, int* __restrict__ deg, int n) {
    int i = blockIdx.x * 256 + threadIdx.x;
    if (i < n) atomicAdd(&deg[dst[i]], 1);
}

__global__ __launch_bounds__(256) void csr_offsets_kernel(const int* __restrict__ deg,
                                                          int* __restrict__ noff,
                                                          int* __restrict__ cur) {
    __shared__ int part[256];
    int g = blockIdx.x, t = threadIdx.x;
    int base = g * NPGC;
    int v0 = deg[base + t * 4 + 0];
    int v1 = deg[base + t * 4 + 1];
    int v2 = deg[base + t * 4 + 2];
    int v3 = deg[base + t * 4 + 3];
    int tot = v0 + v1 + v2 + v3;
    part[t] = tot;
    __syncthreads();
    for (int d = 1; d < 256; d <<= 1) {
        int add = (t >= d) ? part[t - d] : 0;
        __syncthreads();
        part[t] += add;
        __syncthreads();
    }
    int excl = (t == 0) ? 0 : part[t - 1];
    int o = g * (NPGC * 16) + excl;
    int i0 = base + t * 4;
    noff[i0 + 0] = o;            cur[i0 + 0] = o;
    noff[i0 + 1] = o + v0;       cur[i0 + 1] = o + v0;
    noff[i0 + 2] = o + v0 + v1;  cur[i0 + 2] = o + v0 + v1;
    noff[i0 + 3] = o + v0 + v1 + v2; cur[i0 + 3] = o + v0 + v1 + v2;
}

__global__ void csr_fill_kernel(const int* __restrict__ src, const int* __restrict__ dst,
                                int* __restrict__ cur, int* __restrict__ csr, int n) {
    int i = blockIdx.x * 256 + threadIdx.x;
    if (i < n) {
        int p = atomicAdd(&cur[dst[i]], 1);
        csr[p] = src[i];
    }
}

// ---------------- casts ----------------
__global__ void cast_kernel(const float* __restrict__ in, u16* __restrict__ out, int n4) {
    int i = blockIdx.x * 256 + threadIdx.x;
    if (i >= n4) return;
    float4 v = reinterpret_cast<const float4*>(in)[i];
    u32 lo = (u32)fbf(v.x) | ((u32)fbf(v.y) << 16);
    u32 hi = (u32)fbf(v.z) | ((u32)fbf(v.w) << 16);
    uint2 o = {lo, hi};
    reinterpret_cast<uint2*>(out)[i] = o;
}

__global__ void gate_bf16_kernel(const u16* __restrict__ in, const float* __restrict__ gate,
                                 u16* __restrict__ out, int n4) {
    int i = blockIdx.x * 256 + threadIdx.x;
    if (i >= n4) return;
    uint2 v = reinterpret_cast<const uint2*>(in)[i];  // 4 bf16
    float g = gate[i >> 5];                           // 32 uint2 per node (128 feats)
    u32 lo = (u32)fbf(bfu_lo(v.x) * g) | ((u32)fbf(bfu_hi(v.x) * g) << 16);
    u32 hi = (u32)fbf(bfu_lo(v.y) * g) | ((u32)fbf(bfu_hi(v.y) * g) << 16);
    uint2 o = {lo, hi};
    reinterpret_cast<uint2*>(out)[i] = o;
}

// WT[l][col][k]: 3 weight sets at once. l = blockIdx.y.
__global__ void prep_w_kernel(const float* __restrict__ Wr1, const float* __restrict__ Wo1,
                              const float* __restrict__ Wr2, const float* __restrict__ Wo2,
                              const float* __restrict__ Wr3, const float* __restrict__ Wo3,
                              u16* __restrict__ WT) {
    int l = blockIdx.y;
    const float* Wrel = l == 0 ? Wr1 : (l == 1 ? Wr2 : Wr3);
    const float* Wroot = l == 0 ? Wo1 : (l == 1 ? Wo2 : Wo3);
    int idx = blockIdx.x * 256 + threadIdx.x;  // 32768
    int col = idx >> 7, k = idx & 127;
    float v = (col < 128) ? Wrel[k * 128 + col] : Wroot[k * 128 + (col - 128)];
    WT[l * 32768 + idx] = fbf(v);
}

// ---------------- GEMM ----------------
// blockIdx.y==0: rel cols  -> YREL fp32 [N][128]  (gathered 16x downstream -> fp32 kills unpack VALU)
// blockIdx.y==1: root cols -> YROOT bf16 [N][128] (read once downstream)
__global__ __launch_bounds__(256, 2) void gemm_kernel(const u16* __restrict__ X,
                                                      const u16* __restrict__ WT,
                                                      float* __restrict__ YREL,
                                                      u16* __restrict__ YROOT) {
    __shared__ u16 As[128][72];
    __shared__ u16 Bs[128][72];
    int rb = blockIdx.x * 128;
    int cb = blockIdx.y * 128;
    int tid = threadIdx.x;
    int lane = tid & 63, wid = tid >> 6;
    int wr = (wid >> 1) << 6, wc = (wid & 1) << 6;
    int lr = lane & 15, lk = (lane >> 4) << 3;
    f32x4 acc[4][4] = {};

    for (int half = 0; half < 2; ++half) {
        int k0 = half << 6;
        if (half) __syncthreads();
        for (int i = tid; i < 1024; i += 256) {
            int r = i >> 3, c = (i & 7) << 3;
            *reinterpret_cast<uint4*>(&As[r][c]) =
                *reinterpret_cast<const uint4*>(X + (rb + r) * 128 + k0 + c);
            *reinterpret_cast<uint4*>(&Bs[r][c]) =
                *reinterpret_cast<const uint4*>(WT + (cb + r) * 128 + k0 + c);
        }
        __syncthreads();
        for (int kk = 0; kk < 64; kk += 32) {
            bf16x8 a[4], b[4];
            for (int m = 0; m < 4; ++m)
                a[m] = *reinterpret_cast<const bf16x8*>(&As[wr + m * 16 + lr][kk + lk]);
            for (int n = 0; n < 4; ++n)
                b[n] = *reinterpret_cast<const bf16x8*>(&Bs[wc + n * 16 + lr][kk + lk]);
            for (int m = 0; m < 4; ++m)
                for (int n = 0; n < 4; ++n)
                    acc[m][n] = __builtin_amdgcn_mfma_f32_16x16x32_bf16(a[m], b[n], acc[m][n], 0, 0, 0);
        }
    }
    int orow0 = rb + wr + ((lane >> 4) << 2);
    int ocl = wc + (lane & 15);  // local col in [0,128)
    if (blockIdx.y == 0) {
        for (int m = 0; m < 4; ++m)
            for (int n = 0; n < 4; ++n)
                for (int r = 0; r < 4; ++r)
                    YREL[(size_t)(orow0 + m * 16 + r) * 128 + ocl + n * 16] = acc[m][n][r];
    } else {
        for (int m = 0; m < 4; ++m)
            for (int n = 0; n < 4; ++n)
                for (int r = 0; r < 4; ++r)
                    YROOT[(size_t)(orow0 + m * 16 + r) * 128 + ocl + n * 16] = fbf(acc[m][n][r]);
    }
}

// full-group accumulate (no mask) / tail-group (masked) — wave-uniform branch
__device__ __forceinline__ void accg(const float2* buf, int g8, int dgc, float& a0, float& a1) {
    if (g8 + 8 <= dgc) {
#pragma unroll
        for (int j = 0; j < 8; ++j) { a0 += buf[j].x; a1 += buf[j].y; }
    } else {
#pragma unroll
        for (int j = 0; j < 8; ++j) {
            if (g8 + j < dgc) { a0 += buf[j].x; a1 += buf[j].y; }
        }
    }
}

// ---------------- fused aggregate + combine + relu + pool (+score) ----------------
__global__ __launch_bounds__(256) void agg_kernel(const float* __restrict__ YREL,
                                                  const u16* __restrict__ YROOT,
                                                  const int* __restrict__ csr,
                                                  const int* __restrict__ noff,
                                                  const int* __restrict__ deg,
                                                  const float* __restrict__ bias,
                                                  const float* __restrict__ keep,
                                                  u16* __restrict__ outb,
                                                  const float* __restrict__ wsrel,
                                                  const float* __restrict__ wsroot,
                                                  float* __restrict__ srel,
                                                  float* __restrict__ sroot,
                                                  float* __restrict__ xsp,
                                                  int base, float invdenom) {
    __shared__ float pool[4][128];
    // XCD-aware swizzle: 16384 blocks, 8 XCDs -> XCD i gets blocks [i*2048,(i+1)*2048)
    int blk = (blockIdx.x & 7) * 2048 + (blockIdx.x >> 3);
    int wid = threadIdx.x >> 6, lane = threadIdx.x & 63;
    int node = blk * 4 + wid;

    float r0 = 0.f, r1 = 0.f;
    float ki = keep ? keep[node] : 1.0f;
    bool skip = keep && (ki == 0.f);  // wave-uniform: conv3 drops non-kept nodes

    if (!skip) {
        int off = noff[node], dg = deg[node];
        u32 vr = *reinterpret_cast<const u32*>(YROOT + (size_t)node * 128 + lane * 2);
        float2 bb = reinterpret_cast<const float2*>(bias)[lane];

        int sid = (lane < dg) ? csr[off + lane] : 0;
        float cnt;
        if (keep) {
            float kw = (lane < dg) ? keep[sid] : 0.f;
            for (int d = 1; d < 64; d <<= 1) kw += __shfl_xor(kw, d, 64);
            cnt = kw;
        } else {
            cnt = (float)dg;
        }

        int dgc = dg < 64 ? dg : 64;
        float a0 = 0.f, a1 = 0.f;

#define LOADG(buf, g)                                                                     \
    _Pragma("unroll") for (int j = 0; j < 8; ++j) {                                       \
        int s_ = __builtin_amdgcn_readlane(sid, (g) * 8 + j);                             \
        buf[j] = *reinterpret_cast<const float2*>(YREL + (size_t)s_ * 128 + lane * 2);    \
    }

        if (dgc > 0) {
            float2 va[8], vb[8];
            int ng = (dgc + 7) >> 3;
            LOADG(va, 0)
            int g = 0;
            for (; g + 2 < ng; g += 2) {
                LOADG(vb, g + 1)
                accg(va, g * 8, dgc, a0, a1);
                LOADG(va, g + 2)
                accg(vb, (g + 1) * 8, dgc, a0, a1);
            }
            if (g + 1 < ng) {
                LOADG(vb, g + 1)
                accg(va, g * 8, dgc, a0, a1);
                accg(vb, (g + 1) * 8, dgc, a0, a1);
            } else {
                accg(va, g * 8, dgc, a0, a1);
            }
        }
#undef LOADG

        for (int e = 64; e < dg; ++e) {  // astronomically rare: degree > 64
            int s = csr[off + e];
            if (keep) cnt += keep[s];
            float2 v = *reinterpret_cast<const float2*>(YREL + (size_t)s * 128 + lane * 2);
            a0 += v.x;
            a1 += v.y;
        }

        float inv = ki / fmaxf(cnt, 1.0f);
        r0 = fmaxf(a0 * inv + bb.x + bfu_lo(vr), 0.f);
        r1 = fmaxf(a1 * inv + bb.y + bfu_hi(vr), 0.f);

        if (outb) {
            u32 p = ((u32)fbf(r1) << 16) | (u32)fbf(r0);
            *reinterpret_cast<u32*>(outb + (size_t)node * 128 + lane * 2) = p;
        }

        if (srel) {  // SAGPool score partial dots (conv2 only)
            float2 w0 = reinterpret_cast<const float2*>(wsrel)[lane];
            float2 w1 = reinterpret_cast<const float2*>(wsroot)[lane];
            float pr = r0 * w0.x + r1 * w0.y;
            float po = r0 * w1.x + r1 * w1.y;
            for (int d = 1; d < 64; d <<= 1) {
                pr += __shfl_xor(pr, d, 64);
                po += __shfl_xor(po, d, 64);
            }
            if (lane == 0) { srel[node] = pr; sroot[node] = po; }
        }
    }

    // pool: LDS partial across the block's 4 nodes, one atomic per feature into
    // this block's bucket (16 buckets per graph)
    pool[wid][lane * 2] = r0;
    pool[wid][lane * 2 + 1] = r1;
    __syncthreads();
    int t = threadIdx.x;
    if (t < 128) {
        float s = pool[0][t] + pool[1][t] + pool[2][t] + pool[3][t];
        int g = blk >> 8;              // 256 blocks per graph (after swizzle)
        int bucket = blk & 15;
        atomicAdd(&xsp[(g * 16 + bucket) * 384 + base + t], s * invdenom);
    }
}

__global__ void score_agg_kernel(const float* __restrict__ srel, const float* __restrict__ sroot,
                                 const float* __restrict__ bs, const int* __restrict__ csr,
                                 const int* __restrict__ noff, const int* __restrict__ deg,
                                 float* __restrict__ score) {
    int i = blockIdx.x * 256 + threadIdx.x;
    if (i >= NN) return;
    int off = noff[i], dg = deg[i];
    float s = 0.f;
    for (int e = 0; e < dg; ++e) s += srel[csr[off + e]];
    score[i] = s / fmaxf((float)dg, 1.0f) + bs[0] + sroot[i];
}

// ---------------- per-graph top-K via bitonic sort (desc score, asc idx tiebreak)
__global__ __launch_bounds__(1024) void topk_kernel(const float* __restrict__ score,
                                                    float* __restrict__ keep,
                                                    float* __restrict__ gate) {
    __shared__ float sc[NPGC];
    __shared__ int si[NPGC];
    int g = blockIdx.x, t = threadIdx.x;
    sc[t] = score[g * NPGC + t];
    si[t] = t;
    __syncthreads();
    for (int k = 2; k <= NPGC; k <<= 1) {
        for (int j = k >> 1; j > 0; j >>= 1) {
            int ixj = t ^ j;
            if (ixj > t) {
                float a = sc[t], b = sc[ixj];
                int ai = si[t], bi = si[ixj];
                bool less = (a > b) || (a == b && ai < bi);
                bool up = ((t & k) == 0);
                if (less != up) { sc[t] = b; sc[ixj] = a; si[t] = bi; si[ixj] = ai; }
            }
            __syncthreads();
        }
    }
    int node = g * NPGC + si[t];
    float kf = (t < KKEEP) ? 1.f : 0.f;
    keep[node] = kf;
    gate[node] = kf * tanhf(sc[t]);
}

// ---------------- MLP head + log_softmax; one block of 512 per graph.
__global__ __launch_bounds__(512) void mlp_kernel(const float* __restrict__ xsp,
                                                  const float* __restrict__ Wl1,
                                                  const float* __restrict__ bl1,
                                                  const float* __restrict__ Wl2,
                                                  const float* __restrict__ bl2,
                                                  float* __restrict__ out) {
    __shared__ float xsl[384];
    __shared__ float part[4][128];
    __shared__ float wl2s[1280];
    __shared__ float wred[2][10];
    __shared__ float lgs[10];
    int g = blockIdx.x, tid = threadIdx.x;
    int t = tid & 127, kg = tid >> 7;

    for (int i = tid; i < 1280; i += 512) wl2s[i] = Wl2[i];
    if (tid < 384) {
        float s = 0.f;
#pragma unroll
        for (int b = 0; b < 16; ++b) s += xsp[(g * 16 + b) * 384 + tid];
        xsl[tid] = s;
    }
    __syncthreads();

    float p = 0.f;
    int k0 = kg * 96;
#pragma unroll 8
    for (int k = 0; k < 96; ++k) p += xsl[k0 + k] * Wl1[(k0 + k) * 128 + t];
    part[kg][t] = p;
    __syncthreads();

    if (tid < 128) {
        float h = fmaxf(bl1[t] + part[0][t] + part[1][t] + part[2][t] + part[3][t], 0.f);
        float pc[10];
#pragma unroll
        for (int c = 0; c < 10; ++c) pc[c] = h * wl2s[t * 10 + c];
#pragma unroll
        for (int d = 1; d < 64; d <<= 1) {
#pragma unroll
            for (int c = 0; c < 10; ++c) pc[c] += __shfl_xor(pc[c], d, 64);
        }
        if ((t & 63) == 0) {
#pragma unroll
            for (int c = 0; c < 10; ++c) wred[t >> 6][c] = pc[c];
        }
    }
    __syncthreads();
    if (tid < 10) lgs[tid] = wred[0][tid] + wred[1][tid] + bl2[tid];
    __syncthreads();
    if (tid < 10) {
        float m = lgs[0];
#pragma unroll
        for (int c = 1; c < 10; ++c) m = fmaxf(m, lgs[c]);
        float s = 0.f;
#pragma unroll
        for (int c = 0; c < 10; ++c) s += expf(lgs[c] - m);
        out[g * 10 + tid] = lgs[tid] - m - logf(s);
    }
}

extern "C" void kernel_launch(void* const* d_in, const int* in_sizes, int n_in,
                              void* d_out, int out_size, void* d_ws, size_t ws_size,
                              hipStream_t stream) {
    const float* x       = (const float*)d_in[0];
    const int*   src     = (const int*)d_in[1];
    const int*   dst     = (const int*)d_in[2];
    const float* W1_rel  = (const float*)d_in[3];
    const float* b1      = (const float*)d_in[4];
    const float* W1_root = (const float*)d_in[5];
    const float* W2_rel  = (const float*)d_in[6];
    const float* b2      = (const float*)d_in[7];
    const float* W2_root = (const float*)d_in[8];
    const float* W3_rel  = (const float*)d_in[9];
    const float* b3      = (const float*)d_in[10];
    const float* W3_root = (const float*)d_in[11];
    const float* Ws_rel  = (const float*)d_in[12];
    const float* bs      = (const float*)d_in[13];
    const float* Ws_root = (const float*)d_in[14];
    const float* Wl1     = (const float*)d_in[15];
    const float* bl1     = (const float*)d_in[16];
    const float* Wl2     = (const float*)d_in[17];
    const float* bl2     = (const float*)d_in[18];

    char* ws = (char*)d_ws;
    size_t off = 0;
    auto alloc = [&](size_t bytes) -> void* {
        void* p = ws + off;
        off += (bytes + 255) & ~(size_t)255;
        return p;
    };
    u16*   XB    = (u16*)alloc((size_t)NN * 128 * 2);   // gemm input
    u16*   X2B   = (u16*)alloc((size_t)NN * 128 * 2);   // conv2 output (pre-gate)
    float* YREL  = (float*)alloc((size_t)NN * 128 * 4); // gemm rel output (fp32, gathered)
    u16*   YROOT = (u16*)alloc((size_t)NN * 128 * 2);   // gemm root output (bf16, read once)
    u16*   WT    = (u16*)alloc(3 * 256 * 128 * 2);      // 3 weight sets
    float* SREL  = (float*)alloc(NN * 4);
    float* SROOT = (float*)alloc(NN * 4);
    float* SCORE = (float*)alloc(NN * 4);
    float* GATE  = (float*)alloc(NN * 4);
    float* KEEP  = (float*)alloc(NN * 4);
    int*   DEG   = (int*)alloc(NN * 4);
    int*   NOFF  = (int*)alloc(NN * 4);
    int*   CUR   = (int*)alloc(NN * 4);
    int*   CSR   = (int*)alloc((size_t)EE * 4);
    float* XSP   = (float*)alloc((size_t)BG * 16 * 384 * 4);  // bucketed pool partials
    (void)ws_size; (void)n_in; (void)in_sizes; (void)out_size;

    hipMemsetAsync(DEG, 0, NN * 4, stream);
    hipMemsetAsync(XSP, 0, (size_t)BG * 16 * 384 * 4, stream);

    // CSR build (by dst)
    deg_count_kernel<<<EE / 256, 256, 0, stream>>>(dst, DEG, EE);
    csr_offsets_kernel<<<BG, 256, 0, stream>>>(DEG, NOFF, CUR);
    csr_fill_kernel<<<EE / 256, 256, 0, stream>>>(src, dst, CUR, CSR, EE);

    // cast input to bf16 + prep all 3 weight sets
    cast_kernel<<<(NN * 128 / 4) / 256, 256, 0, stream>>>(x, XB, NN * 128 / 4);
    prep_w_kernel<<<dim3(128, 3), 256, 0, stream>>>(W1_rel, W1_root, W2_rel, W2_root,
                                                    W3_rel, W3_root, WT);

    // ---- conv1 ----
    gemm_kernel<<<dim3(NN / 128, 2), 256, 0, stream>>>(XB, WT, YREL, YROOT);
    agg_kernel<<<NN / 4, 256, 0, stream>>>(YREL, YROOT, CSR, NOFF, DEG, b1, nullptr, XB,
                                           nullptr, nullptr, nullptr, nullptr,
                                           XSP, 0, 1.f / 1024.f);

    // ---- conv2 (+ fused score dots) ----
    gemm_kernel<<<dim3(NN / 128, 2), 256, 0, stream>>>(XB, WT + 32768, YREL, YROOT);
    agg_kernel<<<NN / 4, 256, 0, stream>>>(YREL, YROOT, CSR, NOFF, DEG, b2, nullptr, X2B,
                                           Ws_rel, Ws_root, SREL, SROOT,
                                           XSP, 128, 1.f / 1024.f);

    // ---- SAGPooling ----
    score_agg_kernel<<<NN / 256, 256, 0, stream>>>(SREL, SROOT, bs, CSR, NOFF, DEG, SCORE);
    topk_kernel<<<BG, 1024, 0, stream>>>(SCORE, KEEP, GATE);
    gate_bf16_kernel<<<(NN * 128 / 4) / 256, 256, 0, stream>>>(X2B, GATE, XB, NN * 128 / 4);

    // ---- conv3 (masked) ----
    gemm_kernel<<<dim3(NN / 128, 2), 256, 0, stream>>>(XB, WT + 65536, YREL, YROOT);
    agg_kernel<<<NN / 4, 256, 0, stream>>>(YREL, YROOT, CSR, NOFF, DEG, b3, KEEP, nullptr,
                                           nullptr, nullptr, nullptr, nullptr,
                                           XSP, 256, 1.f / (float)KKEEP);

    // ---- MLP head ----
    mlp_kernel<<<BG, 512, 0, stream>>>(XSP, Wl1, bl1, Wl2, bl2, (float*)d_out);
}

// Round 7
// 220.365 us; speedup vs baseline: 1.4537x; 1.4537x over previous
//
#include <hip/hip_runtime.h>
#include <hip/hip_bf16.h>

#define NN 65536
#define EE 1048576
#define BG 64
#define NPGC 1024
#define KKEEP 820

typedef unsigned short u16;
typedef unsigned int u32;
typedef __attribute__((ext_vector_type(4))) float f32x4;
typedef __attribute__((ext_vector_type(8))) short bf16x8;

__device__ __forceinline__ float bfu_lo(u32 u) {  // low bf16 -> f32
    u32 x = u << 16;
    return __builtin_bit_cast(float, x);
}
__device__ __forceinline__ float bfu_hi(u32 u) {  // high bf16 -> f32
    u32 x = u & 0xffff0000u;
    return __builtin_bit_cast(float, x);
}
__device__ __forceinline__ u16 fbf(float f) {
    __hip_bfloat16 h = __float2bfloat16(f);
    return __builtin_bit_cast(u16, h);
}

// ---------------- CSR build: one block per graph, all in LDS ----------------
// histogram (LDS atomics) -> exclusive scan -> LDS-cursor fill. Replaces 3
// global-atomic kernels.
__global__ __launch_bounds__(1024) void csr_build_kernel(const int* __restrict__ src,
                                                         const int* __restrict__ dst,
                                                         int* __restrict__ noff,
                                                         int* __restrict__ deg,
                                                         int* __restrict__ csr) {
    __shared__ int hist[NPGC];
    __shared__ int scan[NPGC];
    int g = blockIdx.x, t = threadIdx.x;
    hist[t] = 0;
    __syncthreads();
    int ebase = g * 16384;
    for (int i = t; i < 16384; i += 1024) atomicAdd(&hist[dst[ebase + i] & 1023], 1);
    __syncthreads();
    int d = hist[t];
    scan[t] = d;
    __syncthreads();
    for (int s = 1; s < NPGC; s <<= 1) {
        int add = (t >= s) ? scan[t - s] : 0;
        __syncthreads();
        scan[t] += add;
        __syncthreads();
    }
    int excl = scan[t] - d;
    int node = g * NPGC + t;
    deg[node] = d;
    noff[node] = ebase + excl;
    hist[t] = excl;  // becomes the fill cursor
    __syncthreads();
    for (int i = t; i < 16384; i += 1024) {
        int dl = dst[ebase + i] & 1023;
        int p = atomicAdd(&hist[dl], 1);
        csr[ebase + p] = src[ebase + i];
    }
}

// ---------------- casts ----------------
__global__ void cast_kernel(const float* __restrict__ in, u16* __restrict__ out, int n4) {
    int i = blockIdx.x * 256 + threadIdx.x;
    if (i >= n4) return;
    float4 v = reinterpret_cast<const float4*>(in)[i];
    u32 lo = (u32)fbf(v.x) | ((u32)fbf(v.y) << 16);
    u32 hi = (u32)fbf(v.z) | ((u32)fbf(v.w) << 16);
    uint2 o = {lo, hi};
    reinterpret_cast<uint2*>(out)[i] = o;
}

__global__ void gate_bf16_kernel(const u16* __restrict__ in, const float* __restrict__ gate,
                                 u16* __restrict__ out, int n4) {
    int i = blockIdx.x * 256 + threadIdx.x;
    if (i >= n4) return;
    uint2 v = reinterpret_cast<const uint2*>(in)[i];  // 4 bf16
    float g = gate[i >> 5];                           // 32 uint2 per node (128 feats)
    u32 lo = (u32)fbf(bfu_lo(v.x) * g) | ((u32)fbf(bfu_hi(v.x) * g) << 16);
    u32 hi = (u32)fbf(bfu_lo(v.y) * g) | ((u32)fbf(bfu_hi(v.y) * g) << 16);
    uint2 o = {lo, hi};
    reinterpret_cast<uint2*>(out)[i] = o;
}

// WT[l][col][k]: 3 weight sets at once. l = blockIdx.y.
__global__ void prep_w_kernel(const float* __restrict__ Wr1, const float* __restrict__ Wo1,
                              const float* __restrict__ Wr2, const float* __restrict__ Wo2,
                              const float* __restrict__ Wr3, const float* __restrict__ Wo3,
                              u16* __restrict__ WT) {
    int l = blockIdx.y;
    const float* Wrel = l == 0 ? Wr1 : (l == 1 ? Wr2 : Wr3);
    const float* Wroot = l == 0 ? Wo1 : (l == 1 ? Wo2 : Wo3);
    int idx = blockIdx.x * 256 + threadIdx.x;  // 32768
    int col = idx >> 7, k = idx & 127;
    float v = (col < 128) ? Wrel[k * 128 + col] : Wroot[k * 128 + (col - 128)];
    WT[l * 32768 + idx] = fbf(v);
}

// ---------------- GEMM: Y[N][256] = X[N][128] @ Wcat[128][256]  (bf16 in/out, fp32 acc)
__global__ __launch_bounds__(256, 2) void gemm_kernel(const u16* __restrict__ X,
                                                      const u16* __restrict__ WT,
                                                      u16* __restrict__ Y) {
    __shared__ u16 As[128][72];
    __shared__ u16 Bs[128][72];
    int rb = blockIdx.x * 128;
    int cb = blockIdx.y * 128;
    int tid = threadIdx.x;
    int lane = tid & 63, wid = tid >> 6;
    int wr = (wid >> 1) << 6, wc = (wid & 1) << 6;
    int lr = lane & 15, lk = (lane >> 4) << 3;
    f32x4 acc[4][4] = {};

    for (int half = 0; half < 2; ++half) {
        int k0 = half << 6;
        if (half) __syncthreads();
        for (int i = tid; i < 1024; i += 256) {
            int r = i >> 3, c = (i & 7) << 3;
            *reinterpret_cast<uint4*>(&As[r][c]) =
                *reinterpret_cast<const uint4*>(X + (rb + r) * 128 + k0 + c);
            *reinterpret_cast<uint4*>(&Bs[r][c]) =
                *reinterpret_cast<const uint4*>(WT + (cb + r) * 128 + k0 + c);
        }
        __syncthreads();
        for (int kk = 0; kk < 64; kk += 32) {
            bf16x8 a[4], b[4];
            for (int m = 0; m < 4; ++m)
                a[m] = *reinterpret_cast<const bf16x8*>(&As[wr + m * 16 + lr][kk + lk]);
            for (int n = 0; n < 4; ++n)
                b[n] = *reinterpret_cast<const bf16x8*>(&Bs[wc + n * 16 + lr][kk + lk]);
            for (int m = 0; m < 4; ++m)
                for (int n = 0; n < 4; ++n)
                    acc[m][n] = __builtin_amdgcn_mfma_f32_16x16x32_bf16(a[m], b[n], acc[m][n], 0, 0, 0);
        }
    }
    int orow0 = rb + wr + ((lane >> 4) << 2);
    int ocol0 = cb + wc + (lane & 15);
    for (int m = 0; m < 4; ++m)
        for (int n = 0; n < 4; ++n)
            for (int r = 0; r < 4; ++r)
                Y[(size_t)(orow0 + m * 16 + r) * 256 + ocol0 + n * 16] = fbf(acc[m][n][r]);
}

// ---------------- fused aggregate + combine + relu + pool (+score) ----------------
// 2 nodes per wave: half-wave (32 lanes) per node, uint2 (4 bf16) per lane.
// One 64-lane load = 2 neighbor rows (2x fewer VMEM insts, 2x fewer waves).
// Neighbor-row broadcast via ds_bpermute (DS pipe, overlaps VALU).
__global__ __launch_bounds__(256) void agg_kernel(const u16* __restrict__ Y,
                                                  const int* __restrict__ csr,
                                                  const int* __restrict__ noff,
                                                  const int* __restrict__ deg,
                                                  const float* __restrict__ bias,
                                                  const float* __restrict__ keep,
                                                  u16* __restrict__ outb,
                                                  const float* __restrict__ wsrel,
                                                  const float* __restrict__ wsroot,
                                                  float* __restrict__ srel,
                                                  float* __restrict__ sroot,
                                                  float* __restrict__ xsp,
                                                  int base, float invdenom) {
    __shared__ float pool[4][128];
    // XCD-aware swizzle: 8192 blocks, 8 XCDs -> XCD i gets blocks [i*1024,(i+1)*1024)
    int blk = (blockIdx.x & 7) * 1024 + (blockIdx.x >> 3);
    int wid = threadIdx.x >> 6, lane = threadIdx.x & 63;
    int hl = lane & 31;          // lane within half
    int half = lane >> 5;        // 0: node A, 1: node B
    int node = blk * 8 + wid * 2 + half;

    int off = noff[node], dg = deg[node];
    uint2 vr = *reinterpret_cast<const uint2*>(Y + (size_t)node * 256 + 128 + hl * 4);
    float4 bb = *reinterpret_cast<const float4*>(bias + hl * 4);

    // lane-parallel neighbor index load (covers deg<=32 per node)
    int sid = (hl < dg) ? csr[off + hl] : 0;
    float ki = 1.f, cnt;
    if (keep) {
        ki = keep[node];
        float kw = (hl < dg) ? keep[sid] : 0.f;
#pragma unroll
        for (int d = 1; d < 32; d <<= 1) kw += __shfl_xor(kw, d, 64);
        cnt = kw;
    } else {
        cnt = (float)dg;
    }

    int dgc = dg < 32 ? dg : 32;
    int dgo = __shfl_xor(dgc, 32, 64);
    int dgmax = dgc > dgo ? dgc : dgo;   // identical across the wave
    int dgmin = dgc < dgo ? dgc : dgo;   // identical across the wave
    int hb = half << 7;                  // bpermute byte base of this half

    float a0 = 0.f, a1 = 0.f, a2 = 0.f, a3 = 0.f;

#define LOADG(buf, g)                                                                   \
    _Pragma("unroll") for (int j = 0; j < 8; ++j) {                                     \
        int row_ = __builtin_amdgcn_ds_bpermute(hb + ((g) * 8 + j) * 4, sid);           \
        buf[j] = *reinterpret_cast<const uint2*>(Y + (size_t)row_ * 256 + hl * 4);      \
    }
#define ACCG(buf, g)                                                                    \
    if ((g) * 8 + 8 <= dgmin) {                                                         \
        _Pragma("unroll") for (int j = 0; j < 8; ++j) {                                 \
            a0 += bfu_lo(buf[j].x); a1 += bfu_hi(buf[j].x);                             \
            a2 += bfu_lo(buf[j].y); a3 += bfu_hi(buf[j].y);                             \
        }                                                                               \
    } else {                                                                            \
        _Pragma("unroll") for (int j = 0; j < 8; ++j) {                                 \
            float m_ = ((g) * 8 + j < dgc) ? 1.f : 0.f;                                 \
            a0 += m_ * bfu_lo(buf[j].x); a1 += m_ * bfu_hi(buf[j].x);                   \
            a2 += m_ * bfu_lo(buf[j].y); a3 += m_ * bfu_hi(buf[j].y);                   \
        }                                                                               \
    }

    if (dgmax > 0) {
        uint2 va[8], vb[8];
        int ngw = (dgmax + 7) >> 3;
        LOADG(va, 0)
        int g = 0;
        for (; g + 2 < ngw; g += 2) {
            LOADG(vb, g + 1)
            ACCG(va, g)
            LOADG(va, g + 2)
            ACCG(vb, g + 1)
        }
        if (g + 1 < ngw) {
            LOADG(vb, g + 1)
            ACCG(va, g)
            ACCG(vb, g + 1)
        } else {
            ACCG(va, g)
        }
    }
#undef LOADG
#undef ACCG

    for (int e = 32; e < dg; ++e) {  // rare: degree > 32
        int srow = csr[off + e];
        if (keep) cnt += keep[srow];
        uint2 v = *reinterpret_cast<const uint2*>(Y + (size_t)srow * 256 + hl * 4);
        a0 += bfu_lo(v.x); a1 += bfu_hi(v.x);
        a2 += bfu_lo(v.y); a3 += bfu_hi(v.y);
    }

    float inv = 1.f / fmaxf(cnt, 1.f);
    // ki=0 (conv3 dropped node) zeroes r entirely; gather numerator of kept nodes is
    // already correct because gated inputs zero dropped rows of Y.
    float r0 = fmaxf(a0 * inv + bb.x + bfu_lo(vr.x), 0.f) * ki;
    float r1 = fmaxf(a1 * inv + bb.y + bfu_hi(vr.x), 0.f) * ki;
    float r2 = fmaxf(a2 * inv + bb.z + bfu_lo(vr.y), 0.f) * ki;
    float r3 = fmaxf(a3 * inv + bb.w + bfu_hi(vr.y), 0.f) * ki;

    if (outb) {
        uint2 p;
        p.x = (u32)fbf(r0) | ((u32)fbf(r1) << 16);
        p.y = (u32)fbf(r2) | ((u32)fbf(r3) << 16);
        *reinterpret_cast<uint2*>(outb + (size_t)node * 128 + hl * 4) = p;
    }

    if (srel) {  // SAGPool score partial dots (conv2 only)
        float4 w0 = *reinterpret_cast<const float4*>(wsrel + hl * 4);
        float4 w1 = *reinterpret_cast<const float4*>(wsroot + hl * 4);
        float pr = r0 * w0.x + r1 * w0.y + r2 * w0.z + r3 * w0.w;
        float po = r0 * w1.x + r1 * w1.y + r2 * w1.z + r3 * w1.w;
#pragma unroll
        for (int d = 1; d < 32; d <<= 1) {
            pr += __shfl_xor(pr, d, 64);
            po += __shfl_xor(po, d, 64);
        }
        if (hl == 0) { srel[node] = pr; sroot[node] = po; }
    }

    // pool: combine halves via shfl, LDS partial across 4 waves, one atomic per feature
    float s0 = r0 + __shfl_xor(r0, 32, 64);
    float s1 = r1 + __shfl_xor(r1, 32, 64);
    float s2 = r2 + __shfl_xor(r2, 32, 64);
    float s3 = r3 + __shfl_xor(r3, 32, 64);
    if (half == 0) {
        pool[wid][hl * 4 + 0] = s0;
        pool[wid][hl * 4 + 1] = s1;
        pool[wid][hl * 4 + 2] = s2;
        pool[wid][hl * 4 + 3] = s3;
    }
    __syncthreads();
    int t = threadIdx.x;
    if (t < 128) {
        float s = pool[0][t] + pool[1][t] + pool[2][t] + pool[3][t];
        int g = blk >> 7;              // 128 blocks per graph (after swizzle)
        int bucket = blk & 15;
        atomicAdd(&xsp[(g * 16 + bucket) * 384 + base + t], s * invdenom);
    }
}

// ---------------- per-graph top-K (fused score aggregation + bitonic sort) ----------------
__global__ __launch_bounds__(1024) void topk_kernel(const float* __restrict__ srel,
                                                    const float* __restrict__ sroot,
                                                    const float* __restrict__ bs,
                                                    const int* __restrict__ csr,
                                                    const int* __restrict__ noff,
                                                    const int* __restrict__ deg,
                                                    float* __restrict__ keep,
                                                    float* __restrict__ gate) {
    __shared__ float sc[NPGC];
    __shared__ int si[NPGC];
    __shared__ float ssr[NPGC];
    int g = blockIdx.x, t = threadIdx.x;
    int node = g * NPGC + t;
    ssr[t] = srel[node];
    __syncthreads();
    int off = noff[node], dg = deg[node];
    float s = 0.f;
    for (int e = 0; e < dg; ++e) s += ssr[csr[off + e] & 1023];
    sc[t] = s / fmaxf((float)dg, 1.0f) + bs[0] + sroot[node];
    si[t] = t;
    __syncthreads();
    for (int k = 2; k <= NPGC; k <<= 1) {
        for (int j = k >> 1; j > 0; j >>= 1) {
            int ixj = t ^ j;
            if (ixj > t) {
                float a = sc[t], b = sc[ixj];
                int ai = si[t], bi = si[ixj];
                bool less = (a > b) || (a == b && ai < bi);  // desc, idx-asc tiebreak
                bool up = ((t & k) == 0);
                if (less != up) { sc[t] = b; sc[ixj] = a; si[t] = bi; si[ixj] = ai; }
            }
            __syncthreads();
        }
    }
    int onode = g * NPGC + si[t];
    float kf = (t < KKEEP) ? 1.f : 0.f;
    keep[onode] = kf;
    gate[onode] = kf * tanhf(sc[t]);
}

// ---------------- MLP head + log_softmax; one block of 512 per graph.
__global__ __launch_bounds__(512) void mlp_kernel(const float* __restrict__ xsp,
                                                  const float* __restrict__ Wl1,
                                                  const float* __restrict__ bl1,
                                                  const float* __restrict__ Wl2,
                                                  const float* __restrict__ bl2,
                                                  float* __restrict__ out) {
    __shared__ float xsl[384];
    __shared__ float part[4][128];
    __shared__ float wl2s[1280];
    __shared__ float wred[2][10];
    __shared__ float lgs[10];
    int g = blockIdx.x, tid = threadIdx.x;
    int t = tid & 127, kg = tid >> 7;

    for (int i = tid; i < 1280; i += 512) wl2s[i] = Wl2[i];
    if (tid < 384) {
        float s = 0.f;
#pragma unroll
        for (int b = 0; b < 16; ++b) s += xsp[(g * 16 + b) * 384 + tid];
        xsl[tid] = s;
    }
    __syncthreads();

    float p = 0.f;
    int k0 = kg * 96;
#pragma unroll 8
    for (int k = 0; k < 96; ++k) p += xsl[k0 + k] * Wl1[(k0 + k) * 128 + t];
    part[kg][t] = p;
    __syncthreads();

    if (tid < 128) {
        float h = fmaxf(bl1[t] + part[0][t] + part[1][t] + part[2][t] + part[3][t], 0.f);
        float pc[10];
#pragma unroll
        for (int c = 0; c < 10; ++c) pc[c] = h * wl2s[t * 10 + c];
#pragma unroll
        for (int d = 1; d < 64; d <<= 1) {
#pragma unroll
            for (int c = 0; c < 10; ++c) pc[c] += __shfl_xor(pc[c], d, 64);
        }
        if ((t & 63) == 0) {
#pragma unroll
            for (int c = 0; c < 10; ++c) wred[t >> 6][c] = pc[c];
        }
    }
    __syncthreads();
    if (tid < 10) lgs[tid] = wred[0][tid] + wred[1][tid] + bl2[tid];
    __syncthreads();
    if (tid < 10) {
        float m = lgs[0];
#pragma unroll
        for (int c = 1; c < 10; ++c) m = fmaxf(m, lgs[c]);
        float s = 0.f;
#pragma unroll
        for (int c = 0; c < 10; ++c) s += expf(lgs[c] - m);
        out[g * 10 + tid] = lgs[tid] - m - logf(s);
    }
}

extern "C" void kernel_launch(void* const* d_in, const int* in_sizes, int n_in,
                              void* d_out, int out_size, void* d_ws, size_t ws_size,
                              hipStream_t stream) {
    const float* x       = (const float*)d_in[0];
    const int*   src     = (const int*)d_in[1];
    const int*   dst     = (const int*)d_in[2];
    const float* W1_rel  = (const float*)d_in[3];
    const float* b1      = (const float*)d_in[4];
    const float* W1_root = (const float*)d_in[5];
    const float* W2_rel  = (const float*)d_in[6];
    const float* b2      = (const float*)d_in[7];
    const float* W2_root = (const float*)d_in[8];
    const float* W3_rel  = (const float*)d_in[9];
    const float* b3      = (const float*)d_in[10];
    const float* W3_root = (const float*)d_in[11];
    const float* Ws_rel  = (const float*)d_in[12];
    const float* bs      = (const float*)d_in[13];
    const float* Ws_root = (const float*)d_in[14];
    const float* Wl1     = (const float*)d_in[15];
    const float* bl1     = (const float*)d_in[16];
    const float* Wl2     = (const float*)d_in[17];
    const float* bl2     = (const float*)d_in[18];

    char* ws = (char*)d_ws;
    size_t off = 0;
    auto alloc = [&](size_t bytes) -> void* {
        void* p = ws + off;
        off += (bytes + 255) & ~(size_t)255;
        return p;
    };
    u16*   XB    = (u16*)alloc((size_t)NN * 128 * 2);   // gemm input
    u16*   X2B   = (u16*)alloc((size_t)NN * 128 * 2);   // conv2 output (pre-gate)
    u16*   YB    = (u16*)alloc((size_t)NN * 256 * 2);   // gemm output (rel|root)
    u16*   WT    = (u16*)alloc(3 * 256 * 128 * 2);      // 3 weight sets
    float* SREL  = (float*)alloc(NN * 4);
    float* SROOT = (float*)alloc(NN * 4);
    float* GATE  = (float*)alloc(NN * 4);
    float* KEEP  = (float*)alloc(NN * 4);
    int*   DEG   = (int*)alloc(NN * 4);
    int*   NOFF  = (int*)alloc(NN * 4);
    int*   CSR   = (int*)alloc((size_t)EE * 4);
    float* XSP   = (float*)alloc((size_t)BG * 16 * 384 * 4);  // bucketed pool partials
    (void)ws_size; (void)n_in; (void)in_sizes; (void)out_size;

    hipMemsetAsync(XSP, 0, (size_t)BG * 16 * 384 * 4, stream);

    // CSR build (single kernel, per-graph LDS)
    csr_build_kernel<<<BG, 1024, 0, stream>>>(src, dst, NOFF, DEG, CSR);

    // cast input to bf16 + prep all 3 weight sets
    cast_kernel<<<(NN * 128 / 4) / 256, 256, 0, stream>>>(x, XB, NN * 128 / 4);
    prep_w_kernel<<<dim3(128, 3), 256, 0, stream>>>(W1_rel, W1_root, W2_rel, W2_root,
                                                    W3_rel, W3_root, WT);

    // ---- conv1 ----
    gemm_kernel<<<dim3(NN / 128, 2), 256, 0, stream>>>(XB, WT, YB);
    agg_kernel<<<NN / 8, 256, 0, stream>>>(YB, CSR, NOFF, DEG, b1, nullptr, XB,
                                           nullptr, nullptr, nullptr, nullptr,
                                           XSP, 0, 1.f / 1024.f);

    // ---- conv2 (+ fused score dots) ----
    gemm_kernel<<<dim3(NN / 128, 2), 256, 0, stream>>>(XB, WT + 32768, YB);
    agg_kernel<<<NN / 8, 256, 0, stream>>>(YB, CSR, NOFF, DEG, b2, nullptr, X2B,
                                           Ws_rel, Ws_root, SREL, SROOT,
                                           XSP, 128, 1.f / 1024.f);

    // ---- SAGPooling (score aggregation fused into topk) ----
    topk_kernel<<<BG, 1024, 0, stream>>>(SREL, SROOT, bs, CSR, NOFF, DEG, KEEP, GATE);
    gate_bf16_kernel<<<(NN * 128 / 4) / 256, 256, 0, stream>>>(X2B, GATE, XB, NN * 128 / 4);

    // ---- conv3 (masked) ----
    gemm_kernel<<<dim3(NN / 128, 2), 256, 0, stream>>>(XB, WT + 65536, YB);
    agg_kernel<<<NN / 8, 256, 0, stream>>>(YB, CSR, NOFF, DEG, b3, KEEP, nullptr,
                                           nullptr, nullptr, nullptr, nullptr,
                                           XSP, 256, 1.f / (float)KKEEP);

    // ---- MLP head ----
    mlp_kernel<<<BG, 512, 0, stream>>>(XSP, Wl1, bl1, Wl2, bl2, (float*)d_out);
}

// Round 8
// 209.714 us; speedup vs baseline: 1.5275x; 1.0508x over previous
//
#include <hip/hip_runtime.h>
#include <hip/hip_bf16.h>

#define NN 65536
#define EE 1048576
#define BG 64
#define NPGC 1024
#define KKEEP 820

typedef unsigned short u16;
typedef unsigned int u32;
typedef __attribute__((ext_vector_type(4))) float f32x4;
typedef __attribute__((ext_vector_type(2))) float f32x2;
typedef __attribute__((ext_vector_type(8))) short bf16x8;

__device__ __forceinline__ float bfu_lo(u32 u) {  // low bf16 -> f32
    u32 x = u << 16;
    return __builtin_bit_cast(float, x);
}
__device__ __forceinline__ float bfu_hi(u32 u) {  // high bf16 -> f32
    u32 x = u & 0xffff0000u;
    return __builtin_bit_cast(float, x);
}
__device__ __forceinline__ u16 fbf(float f) {
    __hip_bfloat16 h = __float2bfloat16(f);
    return __builtin_bit_cast(u16, h);
}
__device__ __forceinline__ u32 pack2(float a, float b) {
    return (u32)fbf(a) | ((u32)fbf(b) << 16);
}

// ---------------- CSR build: one block per graph, all in LDS ----------------
__global__ __launch_bounds__(1024) void csr_build_kernel(const int* __restrict__ src,
                                                         const int* __restrict__ dst,
                                                         int* __restrict__ noff,
                                                         int* __restrict__ deg,
                                                         int* __restrict__ csr) {
    __shared__ int hist[NPGC];
    __shared__ int scan[NPGC];
    int g = blockIdx.x, t = threadIdx.x;
    hist[t] = 0;
    __syncthreads();
    int ebase = g * 16384;
    for (int i = t; i < 16384; i += 1024) atomicAdd(&hist[dst[ebase + i] & 1023], 1);
    __syncthreads();
    int d = hist[t];
    scan[t] = d;
    __syncthreads();
    for (int s = 1; s < NPGC; s <<= 1) {
        int add = (t >= s) ? scan[t - s] : 0;
        __syncthreads();
        scan[t] += add;
        __syncthreads();
    }
    int excl = scan[t] - d;
    int node = g * NPGC + t;
    deg[node] = d;
    noff[node] = ebase + excl;
    hist[t] = excl;  // becomes the fill cursor
    __syncthreads();
    for (int i = t; i < 16384; i += 1024) {
        int dl = dst[ebase + i] & 1023;
        int p = atomicAdd(&hist[dl], 1);
        csr[ebase + p] = src[ebase + i];
    }
}

// WT[l][col][k]: 3 weight sets at once. l = blockIdx.y.
__global__ void prep_w_kernel(const float* __restrict__ Wr1, const float* __restrict__ Wo1,
                              const float* __restrict__ Wr2, const float* __restrict__ Wo2,
                              const float* __restrict__ Wr3, const float* __restrict__ Wo3,
                              u16* __restrict__ WT) {
    int l = blockIdx.y;
    const float* Wrel = l == 0 ? Wr1 : (l == 1 ? Wr2 : Wr3);
    const float* Wroot = l == 0 ? Wo1 : (l == 1 ? Wo2 : Wo3);
    int idx = blockIdx.x * 256 + threadIdx.x;  // 32768
    int col = idx >> 7, k = idx & 127;
    float v = (col < 128) ? Wrel[k * 128 + col] : Wroot[k * 128 + (col - 128)];
    WT[l * 32768 + idx] = fbf(v);
}

// ---------------- GEMM: Y[N][256] = A[N][128] @ Wcat[128][256]  (bf16 MFMA, fp32 acc)
// MODE 0: A = bf16 Xb.  MODE 1: A = fp32 Xf (cast fused, conv1).
// MODE 2: A = bf16 Xb * gate[row] (gate fused, conv3).
template <int MODE>
__global__ __launch_bounds__(256, 2) void gemm_kernel(const u16* __restrict__ Xb,
                                                      const float* __restrict__ Xf,
                                                      const float* __restrict__ gate,
                                                      const u16* __restrict__ WT,
                                                      u16* __restrict__ Y) {
    __shared__ u16 As[128][72];
    __shared__ u16 Bs[128][72];
    int rb = blockIdx.x * 128;
    int cb = blockIdx.y * 128;
    int tid = threadIdx.x;
    int lane = tid & 63, wid = tid >> 6;
    int wr = (wid >> 1) << 6, wc = (wid & 1) << 6;
    int lr = lane & 15, lk = (lane >> 4) << 3;
    f32x4 acc[4][4] = {};

    for (int half = 0; half < 2; ++half) {
        int k0 = half << 6;
        if (half) __syncthreads();
        for (int i = tid; i < 1024; i += 256) {
            int r = i >> 3, c = (i & 7) << 3;
            uint4 av;
            if (MODE == 0) {
                av = *reinterpret_cast<const uint4*>(Xb + (size_t)(rb + r) * 128 + k0 + c);
            } else if (MODE == 1) {
                float4 f0 = *reinterpret_cast<const float4*>(Xf + (size_t)(rb + r) * 128 + k0 + c);
                float4 f1 = *reinterpret_cast<const float4*>(Xf + (size_t)(rb + r) * 128 + k0 + c + 4);
                av.x = pack2(f0.x, f0.y);
                av.y = pack2(f0.z, f0.w);
                av.z = pack2(f1.x, f1.y);
                av.w = pack2(f1.z, f1.w);
            } else {
                float g = gate[rb + r];
                uint4 w = *reinterpret_cast<const uint4*>(Xb + (size_t)(rb + r) * 128 + k0 + c);
                av.x = pack2(bfu_lo(w.x) * g, bfu_hi(w.x) * g);
                av.y = pack2(bfu_lo(w.y) * g, bfu_hi(w.y) * g);
                av.z = pack2(bfu_lo(w.z) * g, bfu_hi(w.z) * g);
                av.w = pack2(bfu_lo(w.w) * g, bfu_hi(w.w) * g);
            }
            *reinterpret_cast<uint4*>(&As[r][c]) = av;
            *reinterpret_cast<uint4*>(&Bs[r][c]) =
                *reinterpret_cast<const uint4*>(WT + (cb + r) * 128 + k0 + c);
        }
        __syncthreads();
        for (int kk = 0; kk < 64; kk += 32) {
            bf16x8 a[4], b[4];
            for (int m = 0; m < 4; ++m)
                a[m] = *reinterpret_cast<const bf16x8*>(&As[wr + m * 16 + lr][kk + lk]);
            for (int n = 0; n < 4; ++n)
                b[n] = *reinterpret_cast<const bf16x8*>(&Bs[wc + n * 16 + lr][kk + lk]);
            for (int m = 0; m < 4; ++m)
                for (int n = 0; n < 4; ++n)
                    acc[m][n] = __builtin_amdgcn_mfma_f32_16x16x32_bf16(a[m], b[n], acc[m][n], 0, 0, 0);
        }
    }
    int orow0 = rb + wr + ((lane >> 4) << 2);
    int ocol0 = cb + wc + (lane & 15);
    for (int m = 0; m < 4; ++m)
        for (int n = 0; n < 4; ++n)
            for (int r = 0; r < 4; ++r)
                Y[(size_t)(orow0 + m * 16 + r) * 256 + ocol0 + n * 16] = fbf(acc[m][n][r]);
}

// ---------------- fused aggregate + combine + relu + pool (+score) ----------------
// 2 nodes per wave; packed v_pk_add_f32 accumulate (2 adds/inst, bit-exact).
__global__ __launch_bounds__(256) void agg_kernel(const u16* __restrict__ Y,
                                                  const int* __restrict__ csr,
                                                  const int* __restrict__ noff,
                                                  const int* __restrict__ deg,
                                                  const float* __restrict__ bias,
                                                  const float* __restrict__ keep,
                                                  u16* __restrict__ outb,
                                                  const float* __restrict__ wsrel,
                                                  const float* __restrict__ wsroot,
                                                  float* __restrict__ srel,
                                                  float* __restrict__ sroot,
                                                  float* __restrict__ xsp,
                                                  int base, float invdenom) {
    __shared__ float pool[4][128];
    // XCD-aware swizzle: 8192 blocks, 8 XCDs -> XCD i gets blocks [i*1024,(i+1)*1024)
    int blk = (blockIdx.x & 7) * 1024 + (blockIdx.x >> 3);
    int wid = threadIdx.x >> 6, lane = threadIdx.x & 63;
    int hl = lane & 31;          // lane within half
    int half = lane >> 5;        // 0: node A, 1: node B
    int node = blk * 8 + wid * 2 + half;

    int off = noff[node], dg = deg[node];
    uint2 vr = *reinterpret_cast<const uint2*>(Y + (size_t)node * 256 + 128 + hl * 4);
    float4 bb = *reinterpret_cast<const float4*>(bias + hl * 4);

    // lane-parallel neighbor index load (covers deg<=32 per node)
    int sid = (hl < dg) ? csr[off + hl] : 0;
    float ki = 1.f, cnt;
    if (keep) {
        ki = keep[node];
        float kw = (hl < dg) ? keep[sid] : 0.f;
#pragma unroll
        for (int d = 1; d < 32; d <<= 1) kw += __shfl_xor(kw, d, 64);
        cnt = kw;
    } else {
        cnt = (float)dg;
    }

    int dgc = dg < 32 ? dg : 32;
    int dgo = __shfl_xor(dgc, 32, 64);
    int dgmax = dgc > dgo ? dgc : dgo;   // identical across the wave
    int dgmin = dgc < dgo ? dgc : dgo;   // identical across the wave
    int hb = half << 7;                  // bpermute byte base of this half

    // accL = (feat+0, feat+2) sums; accH = (feat+1, feat+3) sums
    f32x2 accL = {0.f, 0.f}, accH = {0.f, 0.f};

#define LOADG(buf, g)                                                                   \
    _Pragma("unroll") for (int j = 0; j < 8; ++j) {                                     \
        int row_ = __builtin_amdgcn_ds_bpermute(hb + ((g) * 8 + j) * 4, sid);           \
        buf[j] = *reinterpret_cast<const uint2*>(Y + (size_t)row_ * 256 + hl * 4);      \
    }
#define ACCG(buf, g)                                                                    \
    if ((g) * 8 + 8 <= dgmin) {                                                         \
        _Pragma("unroll") for (int j = 0; j < 8; ++j) {                                 \
            f32x2 lo, hi;                                                               \
            lo.x = bfu_lo(buf[j].x); lo.y = bfu_lo(buf[j].y);                           \
            hi.x = bfu_hi(buf[j].x); hi.y = bfu_hi(buf[j].y);                           \
            asm("v_pk_add_f32 %0, %1, %0" : "+v"(accL) : "v"(lo));                      \
            asm("v_pk_add_f32 %0, %1, %0" : "+v"(accH) : "v"(hi));                      \
        }                                                                               \
    } else {                                                                            \
        _Pragma("unroll") for (int j = 0; j < 8; ++j) {                                 \
            float m_ = ((g) * 8 + j < dgc) ? 1.f : 0.f;                                 \
            accL.x += m_ * bfu_lo(buf[j].x); accH.x += m_ * bfu_hi(buf[j].x);           \
            accL.y += m_ * bfu_lo(buf[j].y); accH.y += m_ * bfu_hi(buf[j].y);           \
        }                                                                               \
    }

    if (dgmax > 0) {
        uint2 va[8], vb[8];
        int ngw = (dgmax + 7) >> 3;
        LOADG(va, 0)
        int g = 0;
        for (; g + 2 < ngw; g += 2) {
            LOADG(vb, g + 1)
            ACCG(va, g)
            LOADG(va, g + 2)
            ACCG(vb, g + 1)
        }
        if (g + 1 < ngw) {
            LOADG(vb, g + 1)
            ACCG(va, g)
            ACCG(vb, g + 1)
        } else {
            ACCG(va, g)
        }
    }
#undef LOADG
#undef ACCG

    for (int e = 32; e < dg; ++e) {  // rare: degree > 32
        int srow = csr[off + e];
        if (keep) cnt += keep[srow];
        uint2 v = *reinterpret_cast<const uint2*>(Y + (size_t)srow * 256 + hl * 4);
        accL.x += bfu_lo(v.x); accH.x += bfu_hi(v.x);
        accL.y += bfu_lo(v.y); accH.y += bfu_hi(v.y);
    }

    float inv = 1.f / fmaxf(cnt, 1.f);
    float r0 = fmaxf(accL.x * inv + bb.x + bfu_lo(vr.x), 0.f) * ki;
    float r1 = fmaxf(accH.x * inv + bb.y + bfu_hi(vr.x), 0.f) * ki;
    float r2 = fmaxf(accL.y * inv + bb.z + bfu_lo(vr.y), 0.f) * ki;
    float r3 = fmaxf(accH.y * inv + bb.w + bfu_hi(vr.y), 0.f) * ki;

    if (outb) {
        uint2 p;
        p.x = (u32)fbf(r0) | ((u32)fbf(r1) << 16);
        p.y = (u32)fbf(r2) | ((u32)fbf(r3) << 16);
        *reinterpret_cast<uint2*>(outb + (size_t)node * 128 + hl * 4) = p;
    }

    if (srel) {  // SAGPool score partial dots (conv2 only)
        float4 w0 = *reinterpret_cast<const float4*>(wsrel + hl * 4);
        float4 w1 = *reinterpret_cast<const float4*>(wsroot + hl * 4);
        float pr = r0 * w0.x + r1 * w0.y + r2 * w0.z + r3 * w0.w;
        float po = r0 * w1.x + r1 * w1.y + r2 * w1.z + r3 * w1.w;
#pragma unroll
        for (int d = 1; d < 32; d <<= 1) {
            pr += __shfl_xor(pr, d, 64);
            po += __shfl_xor(po, d, 64);
        }
        if (hl == 0) { srel[node] = pr; sroot[node] = po; }
    }

    // pool: combine halves via shfl, LDS partial across 4 waves, one atomic per feature
    float s0 = r0 + __shfl_xor(r0, 32, 64);
    float s1 = r1 + __shfl_xor(r1, 32, 64);
    float s2 = r2 + __shfl_xor(r2, 32, 64);
    float s3 = r3 + __shfl_xor(r3, 32, 64);
    if (half == 0) {
        pool[wid][hl * 4 + 0] = s0;
        pool[wid][hl * 4 + 1] = s1;
        pool[wid][hl * 4 + 2] = s2;
        pool[wid][hl * 4 + 3] = s3;
    }
    __syncthreads();
    int t = threadIdx.x;
    if (t < 128) {
        float s = pool[0][t] + pool[1][t] + pool[2][t] + pool[3][t];
        int g = blk >> 7;              // 128 blocks per graph (after swizzle)
        int bucket = blk & 15;
        atomicAdd(&xsp[(g * 16 + bucket) * 384 + base + t], s * invdenom);
    }
}

// ---------------- per-graph top-K (fused score aggregation + bitonic sort) ----------------
__global__ __launch_bounds__(1024) void topk_kernel(const float* __restrict__ srel,
                                                    const float* __restrict__ sroot,
                                                    const float* __restrict__ bs,
                                                    const int* __restrict__ csr,
                                                    const int* __restrict__ noff,
                                                    const int* __restrict__ deg,
                                                    float* __restrict__ keep,
                                                    float* __restrict__ gate) {
    __shared__ float sc[NPGC];
    __shared__ int si[NPGC];
    __shared__ float ssr[NPGC];
    int g = blockIdx.x, t = threadIdx.x;
    int node = g * NPGC + t;
    ssr[t] = srel[node];
    __syncthreads();
    int off = noff[node], dg = deg[node];
    float s = 0.f;
    for (int e = 0; e < dg; ++e) s += ssr[csr[off + e] & 1023];
    sc[t] = s / fmaxf((float)dg, 1.0f) + bs[0] + sroot[node];
    si[t] = t;
    __syncthreads();
    for (int k = 2; k <= NPGC; k <<= 1) {
        for (int j = k >> 1; j > 0; j >>= 1) {
            int ixj = t ^ j;
            if (ixj > t) {
                float a = sc[t], b = sc[ixj];
                int ai = si[t], bi = si[ixj];
                bool less = (a > b) || (a == b && ai < bi);  // desc, idx-asc tiebreak
                bool up = ((t & k) == 0);
                if (less != up) { sc[t] = b; sc[ixj] = a; si[t] = bi; si[ixj] = ai; }
            }
            __syncthreads();
        }
    }
    int onode = g * NPGC + si[t];
    float kf = (t < KKEEP) ? 1.f : 0.f;
    keep[onode] = kf;
    gate[onode] = kf * tanhf(sc[t]);
}

// ---------------- MLP head + log_softmax; one block of 512 per graph.
__global__ __launch_bounds__(512) void mlp_kernel(const float* __restrict__ xsp,
                                                  const float* __restrict__ Wl1,
                                                  const float* __restrict__ bl1,
                                                  const float* __restrict__ Wl2,
                                                  const float* __restrict__ bl2,
                                                  float* __restrict__ out) {
    __shared__ float xsl[384];
    __shared__ float part[4][128];
    __shared__ float wl2s[1280];
    __shared__ float wred[2][10];
    __shared__ float lgs[10];
    int g = blockIdx.x, tid = threadIdx.x;
    int t = tid & 127, kg = tid >> 7;

    for (int i = tid; i < 1280; i += 512) wl2s[i] = Wl2[i];
    if (tid < 384) {
        float s = 0.f;
#pragma unroll
        for (int b = 0; b < 16; ++b) s += xsp[(g * 16 + b) * 384 + tid];
        xsl[tid] = s;
    }
    __syncthreads();

    float p = 0.f;
    int k0 = kg * 96;
#pragma unroll 8
    for (int k = 0; k < 96; ++k) p += xsl[k0 + k] * Wl1[(k0 + k) * 128 + t];
    part[kg][t] = p;
    __syncthreads();

    if (tid < 128) {
        float h = fmaxf(bl1[t] + part[0][t] + part[1][t] + part[2][t] + part[3][t], 0.f);
        float pc[10];
#pragma unroll
        for (int c = 0; c < 10; ++c) pc[c] = h * wl2s[t * 10 + c];
#pragma unroll
        for (int d = 1; d < 64; d <<= 1) {
#pragma unroll
            for (int c = 0; c < 10; ++c) pc[c] += __shfl_xor(pc[c], d, 64);
        }
        if ((t & 63) == 0) {
#pragma unroll
            for (int c = 0; c < 10; ++c) wred[t >> 6][c] = pc[c];
        }
    }
    __syncthreads();
    if (tid < 10) lgs[tid] = wred[0][tid] + wred[1][tid] + bl2[tid];
    __syncthreads();
    if (tid < 10) {
        float m = lgs[0];
#pragma unroll
        for (int c = 1; c < 10; ++c) m = fmaxf(m, lgs[c]);
        float s = 0.f;
#pragma unroll
        for (int c = 0; c < 10; ++c) s += expf(lgs[c] - m);
        out[g * 10 + tid] = lgs[tid] - m - logf(s);
    }
}

extern "C" void kernel_launch(void* const* d_in, const int* in_sizes, int n_in,
                              void* d_out, int out_size, void* d_ws, size_t ws_size,
                              hipStream_t stream) {
    const float* x       = (const float*)d_in[0];
    const int*   src     = (const int*)d_in[1];
    const int*   dst     = (const int*)d_in[2];
    const float* W1_rel  = (const float*)d_in[3];
    const float* b1      = (const float*)d_in[4];
    const float* W1_root = (const float*)d_in[5];
    const float* W2_rel  = (const float*)d_in[6];
    const float* b2      = (const float*)d_in[7];
    const float* W2_root = (const float*)d_in[8];
    const float* W3_rel  = (const float*)d_in[9];
    const float* b3      = (const float*)d_in[10];
    const float* W3_root = (const float*)d_in[11];
    const float* Ws_rel  = (const float*)d_in[12];
    const float* bs      = (const float*)d_in[13];
    const float* Ws_root = (const float*)d_in[14];
    const float* Wl1     = (const float*)d_in[15];
    const float* bl1     = (const float*)d_in[16];
    const float* Wl2     = (const float*)d_in[17];
    const float* bl2     = (const float*)d_in[18];

    char* ws = (char*)d_ws;
    size_t off = 0;
    auto alloc = [&](size_t bytes) -> void* {
        void* p = ws + off;
        off += (bytes + 255) & ~(size_t)255;
        return p;
    };
    u16*   XB    = (u16*)alloc((size_t)NN * 128 * 2);   // conv1 agg output / conv2 input
    u16*   X2B   = (u16*)alloc((size_t)NN * 128 * 2);   // conv2 output (pre-gate)
    u16*   YB    = (u16*)alloc((size_t)NN * 256 * 2);   // gemm output (rel|root)
    u16*   WT    = (u16*)alloc(3 * 256 * 128 * 2);      // 3 weight sets
    float* SREL  = (float*)alloc(NN * 4);
    float* SROOT = (float*)alloc(NN * 4);
    float* GATE  = (float*)alloc(NN * 4);
    float* KEEP  = (float*)alloc(NN * 4);
    int*   DEG   = (int*)alloc(NN * 4);
    int*   NOFF  = (int*)alloc(NN * 4);
    int*   CSR   = (int*)alloc((size_t)EE * 4);
    float* XSP   = (float*)alloc((size_t)BG * 16 * 384 * 4);  // bucketed pool partials
    (void)ws_size; (void)n_in; (void)in_sizes; (void)out_size;

    hipMemsetAsync(XSP, 0, (size_t)BG * 16 * 384 * 4, stream);

    // CSR build (single kernel, per-graph LDS)
    csr_build_kernel<<<BG, 1024, 0, stream>>>(src, dst, NOFF, DEG, CSR);

    // prep all 3 weight sets
    prep_w_kernel<<<dim3(128, 3), 256, 0, stream>>>(W1_rel, W1_root, W2_rel, W2_root,
                                                    W3_rel, W3_root, WT);

    // ---- conv1 (fp32 input cast fused into gemm) ----
    gemm_kernel<1><<<dim3(NN / 128, 2), 256, 0, stream>>>(nullptr, x, nullptr, WT, YB);
    agg_kernel<<<NN / 8, 256, 0, stream>>>(YB, CSR, NOFF, DEG, b1, nullptr, XB,
                                           nullptr, nullptr, nullptr, nullptr,
                                           XSP, 0, 1.f / 1024.f);

    // ---- conv2 (+ fused score dots) ----
    gemm_kernel<0><<<dim3(NN / 128, 2), 256, 0, stream>>>(XB, nullptr, nullptr, WT + 32768, YB);
    agg_kernel<<<NN / 8, 256, 0, stream>>>(YB, CSR, NOFF, DEG, b2, nullptr, X2B,
                                           Ws_rel, Ws_root, SREL, SROOT,
                                           XSP, 128, 1.f / 1024.f);

    // ---- SAGPooling (score aggregation fused into topk) ----
    topk_kernel<<<BG, 1024, 0, stream>>>(SREL, SROOT, bs, CSR, NOFF, DEG, KEEP, GATE);

    // ---- conv3 (gate fused into gemm A-staging) ----
    gemm_kernel<2><<<dim3(NN / 128, 2), 256, 0, stream>>>(X2B, nullptr, GATE, WT + 65536, YB);
    agg_kernel<<<NN / 8, 256, 0, stream>>>(YB, CSR, NOFF, DEG, b3, KEEP, nullptr,
                                           nullptr, nullptr, nullptr, nullptr,
                                           XSP, 256, 1.f / (float)KKEEP);

    // ---- MLP head ----
    mlp_kernel<<<BG, 512, 0, stream>>>(XSP, Wl1, bl1, Wl2, bl2, (float*)d_out);
}